// Round 7
// baseline (22458.379 us; speedup 1.0000x reference)
//
#include <hip/hip_runtime.h>

typedef __attribute__((ext_vector_type(8))) short short8;
typedef __attribute__((ext_vector_type(4))) float f32x4;
typedef __attribute__((ext_vector_type(4))) int int4v;

#define HD 1024
#define BD 64
#define TD 512
#define BH 65536UL  // 64*1024
#define NBLK 194

// ---------------- workspace layout ----------------
#define M4 4194304UL
#define OFF_WHH0 0UL
#define OFF_WIH1 (1UL * M4)
#define OFF_WHH1 (2UL * M4)
#define OFF_WIH2 (3UL * M4)
#define OFF_WHH2 (4UL * M4)
#define OFF_WOUT (5UL * M4)                 // 128 x 1024 (padded rows zeroed)
#define OFF_H0   (OFF_WOUT + 131072UL)      // [2][64][1024] each; h0,h1,h2 consecutive
#define OFF_H1   (OFF_H0 + 131072UL)
#define OFF_H2   (OFF_H1 + 131072UL)
#define USHORT_TOTAL (OFF_H2 + 131072UL)
#define FBYTE_BASE (USHORT_TOTAL * 2UL)      // 42,991,616
#define FOFF_C0 0UL                          // c stored [j][b] (transposed)
#define FOFF_C1 65536UL
#define FOFF_C2 131072UL
#define FOFF_B0 196608UL                     // combined biases b_ih+b_hh [4096]
#define FOFF_B1 200704UL
#define FOFF_B2 204800UL
#define FOFF_BOUT 208896UL                   // [128], pad zeroed
#define FOFF_CNT 209024UL                    // global grid-barrier counter
#define FOFF_ROSTER 209040UL                 // [16] per-XCD block roster (election)
#define FOFF_XCNT 209056UL                   // [16] per-XCD stage-barrier counters
// prep's tail zeroes fr[208896..209088) (minus bout values) -> covers all above.
#define PREP_TOTAL 21704896UL
// XCD staging region: 8 XCDs x 2 ring slots x 3 layers x BH bf16.
#define STG_BYTE 43827968UL                  // 256B-aligned, past float region
#define STG_NEED 50119424UL                  // STG_BYTE + 8*2*3*BH*2

__device__ __forceinline__ unsigned short f2bf(float f) {
  union { float f; unsigned u; } v; v.f = f;
  unsigned r = v.u + 0x7fffu + ((v.u >> 16) & 1u);  // RNE
  return (unsigned short)(r >> 16);
}
__device__ __forceinline__ float sigmoidf_(float x) {
  return 1.0f / (1.0f + __expf(-x));
}
// LDS bank swizzle (R6-verified): writes ~4-way, reads free.
__device__ __forceinline__ int sw(int gn, int b) {
  return gn * 64 + (b ^ (((gn & 7) << 2) | ((gn >> 3) & 3)));
}

// Agent-scope bypass 16B load (compiler-managed waits; used for staging + fallback).
__device__ __forceinline__ short8 load_h16(const unsigned short* p) {
  union { unsigned long long q[2]; short8 v; } u;
  u.q[0] = __hip_atomic_load((const unsigned long long*)p, __ATOMIC_RELAXED,
                             __HIP_MEMORY_SCOPE_AGENT);
  u.q[1] = __hip_atomic_load(((const unsigned long long*)p) + 1, __ATOMIC_RELAXED,
                             __HIP_MEMORY_SCOPE_AGENT);
  return u.v;
}

// Raw 16B loads for the pipelined GEMM. sc1 = MALL-fresh (fallback path);
// sc0 = L1-bypass, local-L2-served (staged path).
__device__ __forceinline__ void gload16_sc1(int4v& dst, const unsigned short* p) {
  asm volatile("global_load_dwordx4 %0, %1, off sc1" : "=v"(dst) : "v"(p));
}
__device__ __forceinline__ void gload16_sc0(int4v& dst, const unsigned short* p) {
  asm volatile("global_load_dwordx4 %0, %1, off sc0" : "=v"(dst) : "v"(p));
}
#define AWAIT_N(N, a0, a1, a2, a3) \
  asm volatile("s_waitcnt vmcnt(" #N ")" : "+v"(a0), "+v"(a1), "+v"(a2), "+v"(a3))

// Fence-free global grid barrier (monotonic counter).
__device__ __forceinline__ void gridbar(int* cnt, int target) {
  asm volatile("s_waitcnt vmcnt(0)" ::: "memory");
  __syncthreads();
  if (threadIdx.x == 0) {
    __hip_atomic_fetch_add(cnt, 1, __ATOMIC_RELAXED, __HIP_MEMORY_SCOPE_AGENT);
    while (__hip_atomic_load(cnt, __ATOMIC_RELAXED, __HIP_MEMORY_SCOPE_AGENT) < target)
      __builtin_amdgcn_s_sleep(1);
  }
  __syncthreads();
}

// ---------------- prep (unchanged from R6; its tail already zeroes roster/xcnt) --------
__global__ void prep_kernel(const float* __restrict__ Whh0, const float* __restrict__ Wih1,
                            const float* __restrict__ Whh1, const float* __restrict__ Wih2,
                            const float* __restrict__ Whh2, const float* __restrict__ Wout,
                            const float* __restrict__ bih0, const float* __restrict__ bhh0,
                            const float* __restrict__ bih1, const float* __restrict__ bhh1,
                            const float* __restrict__ bih2, const float* __restrict__ bhh2,
                            const float* __restrict__ bout, void* wsv) {
  unsigned short* u = (unsigned short*)wsv;
  float* fr = (float*)((char*)wsv + FBYTE_BASE);
  size_t stride = (size_t)gridDim.x * blockDim.x;
  for (size_t i = (size_t)blockIdx.x * blockDim.x + threadIdx.x; i < PREP_TOTAL; i += stride) {
    if (i < 20971520UL) {
      size_t which = i >> 22;
      size_t off = i & (M4 - 1UL);
      const float* src = (which == 0) ? Whh0 : (which == 1) ? Wih1 :
                         (which == 2) ? Whh1 : (which == 3) ? Wih2 : Whh2;
      u[i] = f2bf(src[off]);
    } else if (i < 21102592UL) {
      size_t k = i - 20971520UL;
      size_t o = k >> 10, kk = k & 1023UL;
      u[i] = (o < 121) ? f2bf(Wout[o * 1024UL + kk]) : (unsigned short)0;
    } else if (i < 21495808UL) {
      u[i] = 0;
    } else if (i < 21692416UL) {
      fr[i - 21495808UL] = 0.0f;
    } else if (i < 21704704UL) {
      size_t k = i - 21692416UL;
      size_t l = k >> 12, n = k & 4095UL;
      const float* bi = (l == 0) ? bih0 : (l == 1) ? bih1 : bih2;
      const float* bh = (l == 0) ? bhh0 : (l == 1) ? bhh1 : bhh2;
      fr[FOFF_B0 + l * 4096UL + n] = bi[n] + bh[n];
    } else {
      size_t k = i - 21704704UL;
      fr[FOFF_BOUT + k] = (k < 121) ? bout[k] : 0.0f;  // zeroes cnt/roster/xcnt too
    }
  }
}

// ---------------- per-XCD staging phase ----------------
// All blocks of an XCD cooperatively copy the just-written h versions
// (version (s-1)-l, i.e. parity ((s-1)-l)&1) from the MALL h buffers into
// this XCD's staging slot (s&1). Producers of step s write the OPPOSITE
// parity, so no race. Then a per-XCD barrier (MALL counter) orders staging
// before consumption.
__device__ __forceinline__ void stage_phase(int s, int tid, int rank, int nx,
                                            const unsigned short* __restrict__ hall,
                                            unsigned short* __restrict__ stgx,
                                            int* xc) {
  unsigned short* dst = stgx + (size_t)(s & 1) * (3 * BH);
  for (int idx = rank * 256 + tid; idx < 24576; idx += nx * 256) {  // 16B chunks
    int l = idx >> 13;          // 8192 chunks per layer
    int ch = idx & 8191;
    int par = ((s - 1) - l) & 1;
    short8 v = load_h16(hall + (size_t)l * 131072UL + (size_t)par * BH + (size_t)ch * 8);
    *(short8*)(dst + (size_t)l * BH + (size_t)ch * 8) = v;
  }
  asm volatile("s_waitcnt vmcnt(0)" ::: "memory");  // stores retired in local L2
  __syncthreads();
  if (tid == 0) {
    __hip_atomic_fetch_add(xc, 1, __ATOMIC_RELAXED, __HIP_MEMORY_SCOPE_AGENT);
    while (__hip_atomic_load(xc, __ATOMIC_RELAXED, __HIP_MEMORY_SCOPE_AGENT) < nx * (s + 1))
      __builtin_amdgcn_s_sleep(1);
  }
  __syncthreads();
}

// ---------------- GEMM slice: register B, 6-deep explicit-vmcnt pipelined A -----------
// STG=true: sc0 loads (local L2). STG=false: sc1 bypass (MALL-fresh fallback).
// Tapered drain -> vmcnt==0 at exit (no in-flight register writes; R5 lesson).
template <int NK, bool STG>
__device__ __forceinline__ void gemm_bw(const unsigned short* __restrict__ arow,
                                        const short8 (&bw)[NK][4],
                                        f32x4 (&acc)[4][4]) {
  static_assert(NK >= 6, "pipeline depth");
  int4v ap[6][4];
#pragma unroll
  for (int g = 0; g < 6; ++g)
#pragma unroll
    for (int mt = 0; mt < 4; ++mt) {
      if (STG) gload16_sc0(ap[g][mt], arow + mt * 16 * HD + g * 32);
      else     gload16_sc1(ap[g][mt], arow + mt * 16 * HD + g * 32);
    }
#pragma unroll
  for (int k = 0; k < NK; ++k) {
    const int sl = k % 6;
    if (k <= NK - 6)          { AWAIT_N(20, ap[sl][0], ap[sl][1], ap[sl][2], ap[sl][3]); }
    else if (NK - 1 - k == 4) { AWAIT_N(16, ap[sl][0], ap[sl][1], ap[sl][2], ap[sl][3]); }
    else if (NK - 1 - k == 3) { AWAIT_N(12, ap[sl][0], ap[sl][1], ap[sl][2], ap[sl][3]); }
    else if (NK - 1 - k == 2) { AWAIT_N(8,  ap[sl][0], ap[sl][1], ap[sl][2], ap[sl][3]); }
    else if (NK - 1 - k == 1) { AWAIT_N(4,  ap[sl][0], ap[sl][1], ap[sl][2], ap[sl][3]); }
    else                      { AWAIT_N(0,  ap[sl][0], ap[sl][1], ap[sl][2], ap[sl][3]); }
#pragma unroll
    for (int mt = 0; mt < 4; ++mt) {
      short8 a = *(short8*)&ap[sl][mt];
#pragma unroll
      for (int ns = 0; ns < 4; ++ns)
        acc[ns][mt] = __builtin_amdgcn_mfma_f32_16x16x32_bf16(a, bw[k][ns], acc[ns][mt], 0, 0, 0);
    }
    if (k + 6 < NK) {
#pragma unroll
      for (int mt = 0; mt < 4; ++mt) {
        if (STG) gload16_sc0(ap[sl][mt], arow + mt * 16 * HD + (k + 6) * 32);
        else     gload16_sc1(ap[sl][mt], arow + mt * 16 * HD + (k + 6) * 32);
      }
    }
  }
}

// ---------------- persistent-weight layer driver ----------------
template <bool L0>
__device__ __forceinline__ void run_layer(
    int wgl, int tid, int delay, int lidx,
    const unsigned short* __restrict__ hinbase,  // MALL upstream h (fallback path)
    unsigned short* __restrict__ hbase,          // MALL own h (writes always; fallback reads)
    float* __restrict__ c,
    const unsigned short* __restrict__ Wih,
    const unsigned short* __restrict__ Whh,
    const float* __restrict__ bias,
    const float* __restrict__ strokes, const float* __restrict__ Wih0,
    float* gbuf, int* cnt,
    const unsigned short* __restrict__ hall, unsigned short* stgx, int rank, int nx, int* xc) {
  constexpr int NK = L0 ? 8 : 16;
  const int lane = tid & 63;
  const int w = tid >> 6;
  const int nl = lane & 15;
  const int kq8 = (lane >> 4) << 3;

  const unsigned short* Wm;
  int k0beg;
  bool useHin;
  if (L0) { Wm = Whh; k0beg = w * 256; useHin = false; }
  else    { Wm = (w < 2) ? Wih : Whh; k0beg = (w & 1) * 512; useHin = (w < 2); }

  short8 bw[NK][4];
#pragma unroll
  for (int ns = 0; ns < 4; ++ns) {
    int jgl = wgl * 16 + ns * 4 + (nl >> 2);
    int row = (nl & 3) * HD + jgl;
    const unsigned short* wr = Wm + (size_t)row * HD + kq8 + k0beg;
#pragma unroll
    for (int k = 0; k < NK; ++k) bw[k][ns] = *(const short8*)(wr + k * 32);
  }

  const int bb = (lane >> 4) << 2;
  float* gs = gbuf + w * 4096;

  for (int s = 0; s < TD + 3; ++s) {
    if (stgx) stage_phase(s, tid, rank, nx, hall, stgx, xc);
    int t = s - delay;
    if (t >= 0 && t < TD) {
      const unsigned short* A;
      if (stgx) {
        const unsigned short* slot = stgx + (size_t)(s & 1) * (3 * BH);
        A = slot + (size_t)(useHin ? (lidx - 1) : lidx) * BH;
      } else {
        A = useHin ? (hinbase + (size_t)(t & 1) * BH)
                   : (hbase + (size_t)((t - 1) & 1) * BH);
      }
      const unsigned short* arow = A + nl * HD + kq8 + k0beg;

      f32x4 acc[4][4];
      const f32x4 z4 = {0.f, 0.f, 0.f, 0.f};
#pragma unroll
      for (int ns = 0; ns < 4; ++ns)
#pragma unroll
        for (int mt = 0; mt < 4; ++mt) acc[ns][mt] = z4;

      if (stgx) gemm_bw<NK, true>(arow, bw, acc);
      else      gemm_bw<NK, false>(arow, bw, acc);

#pragma unroll
      for (int ns = 0; ns < 4; ++ns) {
        int gn = ns * 16 + nl;
#pragma unroll
        for (int mt = 0; mt < 4; ++mt)
#pragma unroll
          for (int r = 0; r < 4; ++r)
            gs[sw(gn, mt * 16 + bb + r)] = acc[ns][mt][r];
      }
      __syncthreads();

      unsigned short* hout = hbase + (size_t)(t & 1) * BH;
#pragma unroll
      for (int it = 0; it < 2; ++it) {
        int item = it * 256 + tid;
        int jp = item >> 6;
        int b = item & 63;
        unsigned hv[2];
#pragma unroll
        for (int u2 = 0; u2 < 2; ++u2) {
          int jj = jp * 2 + u2;
          int j = wgl * 16 + jj;
          float p[4];
#pragma unroll
          for (int g = 0; g < 4; ++g) {
            int a = sw(jj * 4 + g, b);
            p[g] = gbuf[a] + gbuf[4096 + a] + gbuf[8192 + a] + gbuf[12288 + a] + bias[g * HD + j];
          }
          if (L0) {
            const float* xr = strokes + ((size_t)b * TD + t) * 3;
            float x0 = xr[0], x1 = xr[1], x2 = xr[2];
#pragma unroll
            for (int g = 0; g < 4; ++g) {
              const float* wr = Wih0 + (size_t)(g * HD + j) * 3;
              p[g] += x0 * wr[0] + x1 * wr[1] + x2 * wr[2];
            }
          }
          float iv = sigmoidf_(p[0]);
          float fv = sigmoidf_(p[1]);
          float gv = tanhf(p[2]);
          float ov = sigmoidf_(p[3]);
          int ci = j * BD + b;
          float cn = fv * c[ci] + iv * gv;
          c[ci] = cn;
          hv[u2] = (unsigned)f2bf(ov * tanhf(cn));
        }
        unsigned packed = hv[0] | (hv[1] << 16);
        __hip_atomic_store((unsigned*)(hout + (size_t)b * HD + wgl * 16 + jp * 2), packed,
                           __ATOMIC_RELAXED, __HIP_MEMORY_SCOPE_AGENT);
      }
    }
    gridbar(cnt, (s + 2) * NBLK);
  }
}

// ---------------- output projection driver (2 WGs x 64 o-columns) ----------------
__device__ __forceinline__ void run_out(
    int wgo, int tid,
    const unsigned short* __restrict__ h2base,
    const unsigned short* __restrict__ Wo,
    const float* __restrict__ bo,
    float* __restrict__ outp, float* gbuf, int* cnt,
    const unsigned short* __restrict__ hall, unsigned short* stgx, int rank, int nx, int* xc) {
  const int lane = tid & 63;
  const int w = tid >> 6;
  const int nl = lane & 15;
  const int kq8 = (lane >> 4) << 3;
  const int k0beg = w * 256;

  short8 bw[8][4];
#pragma unroll
  for (int ns = 0; ns < 4; ++ns) {
    int o = wgo * 64 + ns * 16 + nl;
    const unsigned short* wr = Wo + (size_t)o * HD + kq8 + k0beg;
#pragma unroll
    for (int k = 0; k < 8; ++k) bw[k][ns] = *(const short8*)(wr + k * 32);
  }

  const int bb = (lane >> 4) << 2;
  float* gs = gbuf + w * 4096;

  for (int s = 0; s < TD + 3; ++s) {
    if (stgx) stage_phase(s, tid, rank, nx, hall, stgx, xc);
    int t = s - 3;
    if (t >= 0 && t < TD) {
      const unsigned short* A;
      if (stgx) A = stgx + (size_t)(s & 1) * (3 * BH) + 2 * BH;
      else      A = h2base + (size_t)(t & 1) * BH;
      const unsigned short* arow = A + nl * HD + kq8 + k0beg;

      f32x4 acc[4][4];
      const f32x4 z4 = {0.f, 0.f, 0.f, 0.f};
#pragma unroll
      for (int ns = 0; ns < 4; ++ns)
#pragma unroll
        for (int mt = 0; mt < 4; ++mt) acc[ns][mt] = z4;

      if (stgx) gemm_bw<8, true>(arow, bw, acc);
      else      gemm_bw<8, false>(arow, bw, acc);

#pragma unroll
      for (int ns = 0; ns < 4; ++ns) {
        int gn = ns * 16 + nl;
#pragma unroll
        for (int mt = 0; mt < 4; ++mt)
#pragma unroll
          for (int r = 0; r < 4; ++r)
            gs[sw(gn, mt * 16 + bb + r)] = acc[ns][mt][r];
      }
      __syncthreads();

#pragma unroll
      for (int it = 0; it < 16; ++it) {
        int item = it * 256 + tid;
        int ol = item >> 6;
        int b = item & 63;
        int o = wgo * 64 + ol;
        int a = sw(ol, b);
        float v = gbuf[a] + gbuf[4096 + a] + gbuf[8192 + a] + gbuf[12288 + a] + bo[o];
        if (o < 121) outp[((size_t)b * TD + t) * 121 + o] = v;
      }
    }
    gridbar(cnt, (s + 2) * NBLK);
  }
}

// ---------------- main kernel ----------------
__global__ void __launch_bounds__(256, 1)
lstm_main(const float* __restrict__ strokes, const float* __restrict__ Wih0,
          float* __restrict__ outp, void* __restrict__ wsv, unsigned long long wssz) {
  __shared__ float gbuf[16384];
  __shared__ int sh_rank, sh_nx;
  unsigned short* u = (unsigned short*)wsv;
  float* fr = (float*)((char*)wsv + FBYTE_BASE);
  int* cnt = (int*)(fr + FOFF_CNT);
  int* roster = (int*)(fr + FOFF_ROSTER);
  int* xcnt = (int*)(fr + FOFF_XCNT);

  const int wg = blockIdx.x;
  const int tid = threadIdx.x;
  const bool stage_ok = (wssz >= STG_NEED);

  // --- XCD identification + roster election (once) ---
  int xcc;
  asm("s_getreg_b32 %0, hwreg(HW_REG_XCC_ID)" : "=s"(xcc));
  xcc &= 15;
  if (tid == 0)
    sh_rank = __hip_atomic_fetch_add(&roster[xcc], 1, __ATOMIC_RELAXED, __HIP_MEMORY_SCOPE_AGENT);
  gridbar(cnt, NBLK);  // all registrations visible
  if (tid == 0)
    sh_nx = __hip_atomic_load(&roster[xcc], __ATOMIC_RELAXED, __HIP_MEMORY_SCOPE_AGENT);
  __syncthreads();
  const int rank = sh_rank, nx = sh_nx;

  unsigned short* stgx = stage_ok
      ? (unsigned short*)((char*)wsv + STG_BYTE) + (size_t)xcc * (2 * 3 * BH) : nullptr;
  int* xc = &xcnt[xcc];
  const unsigned short* hall = u + OFF_H0;

  if (wg < 64) {
    run_layer<true>(wg, tid, 0, 0, nullptr, u + OFF_H0, fr + FOFF_C0,
                    nullptr, u + OFF_WHH0, fr + FOFF_B0, strokes, Wih0, gbuf, cnt,
                    hall, stgx, rank, nx, xc);
  } else if (wg < 128) {
    run_layer<false>(wg - 64, tid, 1, 1, u + OFF_H0, u + OFF_H1, fr + FOFF_C1,
                     u + OFF_WIH1, u + OFF_WHH1, fr + FOFF_B1, nullptr, nullptr, gbuf, cnt,
                     hall, stgx, rank, nx, xc);
  } else if (wg < 192) {
    run_layer<false>(wg - 128, tid, 2, 2, u + OFF_H1, u + OFF_H2, fr + FOFF_C2,
                     u + OFF_WIH2, u + OFF_WHH2, fr + FOFF_B2, nullptr, nullptr, gbuf, cnt,
                     hall, stgx, rank, nx, xc);
  } else {
    run_out(wg - 192, tid, u + OFF_H2, u + OFF_WOUT, fr + FOFF_BOUT, outp, gbuf, cnt,
            hall, stgx, rank, nx, xc);
  }
}

extern "C" void kernel_launch(void* const* d_in, const int* in_sizes, int n_in,
                              void* d_out, int out_size, void* d_ws, size_t ws_size,
                              hipStream_t stream) {
  const float* strokes = (const float*)d_in[0];
  const float* Wih0 = (const float*)d_in[1];
  const float* Whh0 = (const float*)d_in[2];
  const float* bih0 = (const float*)d_in[3];
  const float* bhh0 = (const float*)d_in[4];
  const float* Wih1 = (const float*)d_in[5];
  const float* Whh1 = (const float*)d_in[6];
  const float* bih1 = (const float*)d_in[7];
  const float* bhh1 = (const float*)d_in[8];
  const float* Wih2 = (const float*)d_in[9];
  const float* Whh2 = (const float*)d_in[10];
  const float* bih2 = (const float*)d_in[11];
  const float* bhh2 = (const float*)d_in[12];
  const float* Wout = (const float*)d_in[13];
  const float* bout = (const float*)d_in[14];
  float* outp = (float*)d_out;

  hipLaunchKernelGGL(prep_kernel, dim3(4096), dim3(256), 0, stream,
                     Whh0, Wih1, Whh1, Wih2, Whh2, Wout,
                     bih0, bhh0, bih1, bhh1, bih2, bhh2, bout, d_ws);

  hipLaunchKernelGGL(lstm_main, dim3(NBLK), dim3(256), 0, stream,
                     strokes, Wih0, outp, d_ws, (unsigned long long)ws_size);
}